// Round 8
// baseline (65.115 us; speedup 1.0000x reference)
//
#include <hip/hip_runtime.h>
#include <stdint.h>

#define B_   4
#define CIN  32
#define COUT 32
#define NN   81920
#define KK   10
#define NT   128          // n-tile per block (4 waves x 32)

typedef unsigned short ushort_t;
typedef __attribute__((ext_vector_type(8))) short bf16x8;
typedef __attribute__((ext_vector_type(4))) float f32x4;

// float -> bf16 bits, round-to-nearest-even
__device__ __host__ __forceinline__ ushort_t f2bf(float f) {
    union { float f; unsigned int u; } v; v.f = f;
    unsigned int r = (v.u + 0x7FFFu + ((v.u >> 16) & 1u)) >> 16;
    return (ushort_t)r;
}

// ---------- Kernel 1: transpose+convert (B,C,N) f32 -> xb (B,N,C) bf16 ----------
// Same XCD swizzle as k_main: batch b's xb is WRITTEN by XCD pair {2b,2b+1},
// which later gathers from it (dirty-line L2 affinity).
__global__ __launch_bounds__(256) void k_transpose(const float* __restrict__ in,
                                                   ushort_t* __restrict__ xb) {
    __shared__ float tile[32][65];
    const int bid  = blockIdx.x;
    const int b    = (bid & 7) >> 1;
    const int tl   = (bid >> 3) * 2 + (bid & 1);   // 0..1279
    const int n0   = tl * 64;
    const int tid  = threadIdx.x;

#pragma unroll
    for (int i = 0; i < 8; ++i) {
        const int c = i * 4 + (tid >> 6);
        const int n = tid & 63;
        tile[c][n] = in[((size_t)b * CIN + c) * NN + n0 + n];
    }
    __syncthreads();
#pragma unroll
    for (int i = 0; i < 4; ++i) {
        const int n  = i * 16 + (tid >> 4);
        const int cp = tid & 15;
        const unsigned int u0 = f2bf(tile[2 * cp][n]);
        const unsigned int u1 = f2bf(tile[2 * cp + 1][n]);
        *(unsigned int*)&xb[((size_t)b * NN + n0 + n) * CIN + 2 * cp] = u0 | (u1 << 16);
    }
}

// ---------- Kernel 2: gathered conv as MFMA GEMM, FORCED 20-deep gather MLP ----------
// Gathers are inline-asm global_load_dwordx4 (un-sinkable); counted
// s_waitcnt vmcnt(18-2k) + sched_barrier(0) before each MFMA quad.
// launch_bounds(256,3): 168-VGPR cap so the ~140-reg live set does NOT spill
// (R7's (256,4)=128 cap spilled the B-frags to scratch -> re-serialized).
__global__ __launch_bounds__(256, 3) void k_main(const ushort_t* __restrict__ xb,
                                                 const float* __restrict__ w,
                                                 const float* __restrict__ bias,
                                                 const int* __restrict__ tbl,
                                                 float* __restrict__ out) {
    __shared__ ushort_t Wl[COUT][328];        // [o][k*32+c], pad: A-reads 2-way (free)

    const int tid = threadIdx.x;
    const int bid = blockIdx.x;
    const int b    = (bid & 7) >> 1;          // batch -> XCD pair (L2 locality)
    const int tile = (bid >> 3) * 2 + (bid & 1);
    const int n0   = tile * NT;

    for (int idx = tid; idx < COUT * CIN * KK; idx += 256) {
        const int o = idx / 320, ck = idx % 320;
        const int k = ck >> 5, c = ck & 31;
        Wl[o][ck] = f2bf(w[((size_t)o * CIN + c) * KK + k]);
    }

    const int lane = tid & 63;
    const int wid  = tid >> 6;
    const int wn   = wid * 32;
    const int lr   = lane & 15;
    const int lg   = lane >> 4;

    const int r0 = n0 + wn + lr;
    const int r1 = r0 + 16;

    // bias -> acc and tbl loads BEFORE the barrier (retired before gathers issue)
    f32x4 acc[2][2];
#pragma unroll
    for (int m = 0; m < 2; ++m) {
        f32x4 bv;
#pragma unroll
        for (int r = 0; r < 4; ++r) bv[r] = bias[m * 16 + lg * 4 + r];
        acc[m][0] = bv; acc[m][1] = bv;
    }

    int t0[KK], t1[KK];
#pragma unroll
    for (int k = 0; k < KK; ++k) {
        t0[k] = tbl[(size_t)k * NN + r0];
        t1[k] = tbl[(size_t)k * NN + r1];
    }

    __syncthreads();   // Wl visible; vmcnt drained to 0 here

    const uint64_t xB64 = (uint64_t)(xb + (size_t)b * NN * CIN);

    // byte offsets: row*64 + lg*16  (max ~5.2 MB, fits 32-bit voffset)
    uint32_t off0[KK], off1[KK];
#pragma unroll
    for (int k = 0; k < KK; ++k) {
        off0[k] = ((uint32_t)t0[k] << 6) + (uint32_t)(lg * 16);
        off1[k] = ((uint32_t)t1[k] << 6) + (uint32_t)(lg * 16);
    }

    // prefetch k=0 A-frags (LDS latency overlaps gather issue)
    bf16x8 a0 = *(const bf16x8*)&Wl[lr][0 * 32 + lg * 8];
    bf16x8 a1 = *(const bf16x8*)&Wl[16 + lr][0 * 32 + lg * 8];

    // ---- phase 1: issue ALL 20 gathers via inline asm (un-sinkable) ----
    bf16x8 bf0[KK], bf1[KK];
    __builtin_amdgcn_sched_barrier(0);
#pragma unroll
    for (int k = 0; k < KK; ++k) {
        asm volatile("global_load_dwordx4 %0, %1, %2"
                     : "=v"(bf0[k]) : "v"(off0[k]), "s"(xB64));
        asm volatile("global_load_dwordx4 %0, %1, %2"
                     : "=v"(bf1[k]) : "v"(off1[k]), "s"(xB64));
    }
    __builtin_amdgcn_sched_barrier(0);

    // ---- phase 2: MFMA chain with counted vmcnt; A-frags prefetched 1 ahead ----
#pragma unroll
    for (int k = 0; k < KK; ++k) {
        bf16x8 na0, na1;
        if (k + 1 < KK) {
            na0 = *(const bf16x8*)&Wl[lr][(k + 1) * 32 + lg * 8];
            na1 = *(const bf16x8*)&Wl[16 + lr][(k + 1) * 32 + lg * 8];
        }
        asm volatile("s_waitcnt vmcnt(%0)" :: "i"(18 - 2 * k));
        __builtin_amdgcn_sched_barrier(0);
        acc[0][0] = __builtin_amdgcn_mfma_f32_16x16x32_bf16(a0, bf0[k], acc[0][0], 0, 0, 0);
        acc[1][0] = __builtin_amdgcn_mfma_f32_16x16x32_bf16(a1, bf0[k], acc[1][0], 0, 0, 0);
        acc[0][1] = __builtin_amdgcn_mfma_f32_16x16x32_bf16(a0, bf1[k], acc[0][1], 0, 0, 0);
        acc[1][1] = __builtin_amdgcn_mfma_f32_16x16x32_bf16(a1, bf1[k], acc[1][1], 0, 0, 0);
        a0 = na0; a1 = na1;
    }

#pragma unroll
    for (int m = 0; m < 2; ++m)
#pragma unroll
        for (int nt = 0; nt < 2; ++nt)
#pragma unroll
            for (int r = 0; r < 4; ++r) {
                const int o = m * 16 + lg * 4 + r;
                const int n = n0 + wn + nt * 16 + lr;
                const float v = acc[m][nt][r];
                out[((size_t)(b * COUT + o)) * NN + n] = v > 0.f ? v : 0.f;
            }
}

extern "C" void kernel_launch(void* const* d_in, const int* in_sizes, int n_in,
                              void* d_out, int out_size, void* d_ws, size_t ws_size,
                              hipStream_t stream) {
    const float* inp  = (const float*)d_in[0];
    const float* w    = (const float*)d_in[1];
    const float* bias = (const float*)d_in[2];
    const int*   tbl  = (const int*)d_in[3];

    ushort_t* xb = (ushort_t*)d_ws;                              // 20.97 MB
    float* out = (float*)d_out;

    k_transpose<<<(NN / 64) * B_, 256, 0, stream>>>(inp, xb);
    k_main<<<B_ * (NN / NT), 256, 0, stream>>>(xb, w, bias, tbl, out);
}

// Round 9
// 62.765 us; speedup vs baseline: 1.0374x; 1.0374x over previous
//
#include <hip/hip_runtime.h>
#include <stdint.h>

#define B_   4
#define CIN  32
#define COUT 32
#define NN   81920
#define KK   10
#define NT   128          // n-tile per block (4 waves x 32)
#define DEPTH 6           // rolling B-frag buffer depth (issue 5 ahead)

typedef unsigned short ushort_t;
typedef __attribute__((ext_vector_type(8))) short bf16x8;
typedef __attribute__((ext_vector_type(4))) float f32x4;

// float -> bf16 bits, round-to-nearest-even
__device__ __host__ __forceinline__ ushort_t f2bf(float f) {
    union { float f; unsigned int u; } v; v.f = f;
    unsigned int r = (v.u + 0x7FFFu + ((v.u >> 16) & 1u)) >> 16;
    return (ushort_t)r;
}

// ---------- Kernel 1: transpose+convert (B,C,N) f32 -> xb (B,N,C) bf16 ----------
__global__ __launch_bounds__(256) void k_transpose(const float* __restrict__ in,
                                                   ushort_t* __restrict__ xb) {
    __shared__ float tile[32][65];
    const int bid  = blockIdx.x;
    const int b    = (bid & 7) >> 1;
    const int tl   = (bid >> 3) * 2 + (bid & 1);
    const int n0   = tl * 64;
    const int tid  = threadIdx.x;

#pragma unroll
    for (int i = 0; i < 8; ++i) {
        const int c = i * 4 + (tid >> 6);
        const int n = tid & 63;
        tile[c][n] = in[((size_t)b * CIN + c) * NN + n0 + n];
    }
    __syncthreads();
#pragma unroll
    for (int i = 0; i < 4; ++i) {
        const int n  = i * 16 + (tid >> 4);
        const int cp = tid & 15;
        const unsigned int u0 = f2bf(tile[2 * cp][n]);
        const unsigned int u1 = f2bf(tile[2 * cp + 1][n]);
        *(unsigned int*)&xb[((size_t)b * NN + n0 + n) * CIN + 2 * cp] = u0 | (u1 << 16);
    }
}

// ---------- Kernel 2: rolling 6-deep gather pipeline + MFMA ----------
// Only 12 B-frags (48 VGPRs) live -> no spill pressure; inline-asm loads are
// un-sinkable; counted vmcnt keeps ~10 gathers in flight per wave.
__global__ __launch_bounds__(256, 4) void k_main(const ushort_t* __restrict__ xb,
                                                 const float* __restrict__ w,
                                                 const float* __restrict__ bias,
                                                 const int* __restrict__ tbl,
                                                 float* __restrict__ out) {
    __shared__ ushort_t Wl[COUT][328];        // [o][k*32+c], pad: A-reads 2-way (free)

    const int tid = threadIdx.x;
    const int bid = blockIdx.x;
    const int b    = (bid & 7) >> 1;          // batch -> XCD pair (L2 locality)
    const int tile = (bid >> 3) * 2 + (bid & 1);
    const int n0   = tile * NT;

    for (int idx = tid; idx < COUT * CIN * KK; idx += 256) {
        const int o = idx / 320, ck = idx % 320;
        const int k = ck >> 5, c = ck & 31;
        Wl[o][ck] = f2bf(w[((size_t)o * CIN + c) * KK + k]);
    }

    const int lane = tid & 63;
    const int wid  = tid >> 6;
    const int wn   = wid * 32;
    const int lr   = lane & 15;
    const int lg   = lane >> 4;

    const int r0 = n0 + wn + lr;
    const int r1 = r0 + 16;

    // bias -> acc and tbl loads BEFORE the barrier (retired before gathers issue)
    f32x4 acc[2][2];
#pragma unroll
    for (int m = 0; m < 2; ++m) {
        f32x4 bv;
#pragma unroll
        for (int r = 0; r < 4; ++r) bv[r] = bias[m * 16 + lg * 4 + r];
        acc[m][0] = bv; acc[m][1] = bv;
    }

    int t0[KK], t1[KK];
#pragma unroll
    for (int k = 0; k < KK; ++k) {
        t0[k] = tbl[(size_t)k * NN + r0];
        t1[k] = tbl[(size_t)k * NN + r1];
    }

    __syncthreads();   // Wl visible; vmcnt drained to 0 here

    const uint64_t xB64 = (uint64_t)(xb + (size_t)b * NN * CIN);

    uint32_t off0[KK], off1[KK];
#pragma unroll
    for (int k = 0; k < KK; ++k) {
        off0[k] = ((uint32_t)t0[k] << 6) + (uint32_t)(lg * 16);
        off1[k] = ((uint32_t)t1[k] << 6) + (uint32_t)(lg * 16);
    }

#define GLOAD(dst, off)                                                        \
    asm volatile("global_load_dwordx4 %0, %1, %2"                              \
                 : "=v"(dst) : "v"(off), "s"(xB64))

    // ---- prologue: issue pairs 0..4 (10 loads in flight) ----
    bf16x8 bf0[DEPTH], bf1[DEPTH];
    __builtin_amdgcn_sched_barrier(0);
#pragma unroll
    for (int k = 0; k < 5; ++k) {
        GLOAD(bf0[k], off0[k]);
        GLOAD(bf1[k], off1[k]);
    }
    __builtin_amdgcn_sched_barrier(0);

    // k=0 A-frags
    bf16x8 a0 = *(const bf16x8*)&Wl[lr][0 * 32 + lg * 8];
    bf16x8 a1 = *(const bf16x8*)&Wl[16 + lr][0 * 32 + lg * 8];

    // ---- steady loop: issue k+5, wait pair k (counted), MFMA slot k%6 ----
#pragma unroll
    for (int k = 0; k < KK; ++k) {
        if (k + 5 < KK) {
            GLOAD(bf0[(k + 5) % DEPTH], off0[k + 5]);
            GLOAD(bf1[(k + 5) % DEPTH], off1[k + 5]);
        }
        // outstanding after issue = 2*min(k+6,10); need pair k done:
        asm volatile("s_waitcnt vmcnt(%0)"
                     :: "i"(2 * ((KK > k + 6 ? k + 6 : KK) - k - 1)));
        __builtin_amdgcn_sched_barrier(0);

        bf16x8 na0, na1;
        if (k + 1 < KK) {
            na0 = *(const bf16x8*)&Wl[lr][(k + 1) * 32 + lg * 8];
            na1 = *(const bf16x8*)&Wl[16 + lr][(k + 1) * 32 + lg * 8];
        }
        acc[0][0] = __builtin_amdgcn_mfma_f32_16x16x32_bf16(a0, bf0[k % DEPTH], acc[0][0], 0, 0, 0);
        acc[1][0] = __builtin_amdgcn_mfma_f32_16x16x32_bf16(a1, bf0[k % DEPTH], acc[1][0], 0, 0, 0);
        acc[0][1] = __builtin_amdgcn_mfma_f32_16x16x32_bf16(a0, bf1[k % DEPTH], acc[0][1], 0, 0, 0);
        acc[1][1] = __builtin_amdgcn_mfma_f32_16x16x32_bf16(a1, bf1[k % DEPTH], acc[1][1], 0, 0, 0);
        a0 = na0; a1 = na1;
    }
#undef GLOAD

#pragma unroll
    for (int m = 0; m < 2; ++m)
#pragma unroll
        for (int nt = 0; nt < 2; ++nt)
#pragma unroll
            for (int r = 0; r < 4; ++r) {
                const int o = m * 16 + lg * 4 + r;
                const int n = n0 + wn + nt * 16 + lr;
                const float v = acc[m][nt][r];
                out[((size_t)(b * COUT + o)) * NN + n] = v > 0.f ? v : 0.f;
            }
}

extern "C" void kernel_launch(void* const* d_in, const int* in_sizes, int n_in,
                              void* d_out, int out_size, void* d_ws, size_t ws_size,
                              hipStream_t stream) {
    const float* inp  = (const float*)d_in[0];
    const float* w    = (const float*)d_in[1];
    const float* bias = (const float*)d_in[2];
    const int*   tbl  = (const int*)d_in[3];

    ushort_t* xb = (ushort_t*)d_ws;                              // 20.97 MB
    float* out = (float*)d_out;

    k_transpose<<<(NN / 64) * B_, 256, 0, stream>>>(inp, xb);
    k_main<<<B_ * (NN / NT), 256, 0, stream>>>(xb, w, bias, tbl, out);
}

// Round 10
// 52.749 us; speedup vs baseline: 1.2344x; 1.1899x over previous
//
#include <hip/hip_runtime.h>
#include <stdint.h>

#define B_   4
#define CIN  32
#define COUT 32
#define NN   81920
#define KK   10
#define NT   128          // n-tile per block (4 waves x 32 rows each)

typedef unsigned short ushort_t;
typedef __attribute__((ext_vector_type(8))) short bf16x8;
typedef __attribute__((ext_vector_type(4))) float f32x4;

// float -> bf16 bits, round-to-nearest-even
__device__ __host__ __forceinline__ ushort_t f2bf(float f) {
    union { float f; unsigned int u; } v; v.f = f;
    unsigned int r = (v.u + 0x7FFFu + ((v.u >> 16) & 1u)) >> 16;
    return (ushort_t)r;
}

__device__ __forceinline__ void gl_lds16(const void* g, void* lds) {
    auto gp = (const __attribute__((address_space(1))) unsigned int*)((uintptr_t)g);
    auto lp = (__attribute__((address_space(3))) unsigned int*)((uintptr_t)lds);
    __builtin_amdgcn_global_load_lds(gp, lp, 16, 0, 0);
}

// ---------- Kernel 1: transpose+convert (B,C,N) f32 -> xbp (pair,N,e,C) bf16 ----------
// Batch-PAIR packed layout: row t of pair p = [b=2p (64B) | b=2p+1 (64B)] = one
// full 128B cache line -> one gather line-request serves two batches.
__global__ __launch_bounds__(256) void k_transpose(const float* __restrict__ in,
                                                   ushort_t* __restrict__ xbp) {
    __shared__ float tile[32][65];
    const int b   = blockIdx.y;        // 0..3
    const int p   = b >> 1, e = b & 1;
    const int n0  = blockIdx.x * 64;
    const int tid = threadIdx.x;

#pragma unroll
    for (int i = 0; i < 8; ++i) {
        const int c = i * 4 + (tid >> 6);
        const int n = tid & 63;
        tile[c][n] = in[((size_t)b * CIN + c) * NN + n0 + n];
    }
    __syncthreads();
#pragma unroll
    for (int i = 0; i < 4; ++i) {
        const int n  = i * 16 + (tid >> 4);
        const int cp = tid & 15;
        const unsigned int u0 = f2bf(tile[2 * cp][n]);
        const unsigned int u1 = f2bf(tile[2 * cp + 1][n]);
        *(unsigned int*)&xbp[(size_t)p * NN * 64 + (size_t)(n0 + n) * 64 + e * 32 + 2 * cp]
            = u0 | (u1 << 16);
    }
}

// ---------- Kernel 2: pair-packed gathered conv, wave-private LDS, ZERO k-loop barriers ----
// Each wave stages its own 32 rows (one full 128B line per 8 lanes) and reads only
// those -> no inter-wave sync. Counted vmcnt(4) keeps next stage in flight.
// LDS chunk-XOR swizzle (key row&7) baked into the gather SOURCE address.
__global__ __launch_bounds__(256, 3) void k_main(const ushort_t* __restrict__ xbp,
                                                 const float* __restrict__ w,
                                                 const float* __restrict__ bias,
                                                 const int* __restrict__ tbl,
                                                 float* __restrict__ out) {
    __shared__ ushort_t Wl[COUT][328];     // [o][k*32+c], pad: A-reads conflict-free
    __shared__ ushort_t Xl[2][NT][64];     // [buf][row][8 chunks x 8 ushorts] = 128B rows

    const int tid = threadIdx.x;
    const int bid = blockIdx.x;
    // bid bits: [1:0]=q, [2]=pair, [10:3]=T  ->  XCDs 0-3 serve pair 0, 4-7 pair 1
    const int p    = (bid >> 2) & 1;
    const int tile = (bid >> 3) * 4 + (bid & 3);
    const int n0   = tile * NT;

    // weight convert f32 -> bf16 into LDS (shared by all waves)
    for (int idx = tid; idx < COUT * CIN * KK; idx += 256) {
        const int o = idx / 320, ck = idx % 320;
        const int k = ck >> 5, c = ck & 31;
        Wl[o][ck] = f2bf(w[((size_t)o * CIN + c) * KK + k]);
    }

    const int lane = tid & 63;
    const int wid  = tid >> 6;
    const int wn   = wid * 32;            // wave's private 32-row slice
    const int lr   = lane & 15;
    const int lg   = lane >> 4;
    const int g    = lane >> 3;           // line-group 0..7 (8 lanes per line)
    const int csw  = (lane & 7) ^ g;      // source chunk for XOR-swizzled LDS slot

    // distribute the wave's 320 table entries into 5 regs/lane (shfl'd later)
    int tq[5];
#pragma unroll
    for (int j = 0; j < 5; ++j) {
        const int idx = j * 64 + lane;    // idx = k*32 + ii
        tq[j] = tbl[(size_t)(idx >> 5) * NN + n0 + wn + (idx & 31)];
    }

    f32x4 acc[2][2][2];                   // [m][e][s]
#pragma unroll
    for (int m = 0; m < 2; ++m) {
        f32x4 bv;
#pragma unroll
        for (int r = 0; r < 4; ++r) bv[r] = bias[m * 16 + lg * 4 + r];
#pragma unroll
        for (int e = 0; e < 2; ++e) { acc[m][e][0] = bv; acc[m][e][1] = bv; }
    }

    asm volatile("s_waitcnt vmcnt(0) lgkmcnt(0)" ::: "memory");
    __builtin_amdgcn_s_barrier();         // Wl visible (only barrier in the kernel)

    const ushort_t* pb = xbp + (size_t)p * NN * 64;

    // stage kk into buf: 4 gl_lds per thread; 8 lanes cover one full 128B line
    auto stage = [&](int kk, int buf) {
#pragma unroll
        for (int m = 0; m < 4; ++m) {
            const int idx = kk * 32 + m * 8;                 // + g per lane
            const int t   = __shfl(tq[idx >> 6], (idx & 63) + g, 64);
            gl_lds16(pb + (size_t)t * 64 + csw * 8,
                     &Xl[buf][wn + m * 8 + g][(lane & 7) * 8]);
        }
    };

    stage(0, 0);

#pragma unroll
    for (int k = 0; k < KK; ++k) {
        if (k + 1 < KK) {
            stage(k + 1, (k + 1) & 1);
            asm volatile("s_waitcnt vmcnt(4)" ::: "memory");   // stage k done, k+1 flying
        } else {
            asm volatile("s_waitcnt vmcnt(0)" ::: "memory");
        }
        __builtin_amdgcn_sched_barrier(0);

        const bf16x8 a0 = *(const bf16x8*)&Wl[lr][k * 32 + lg * 8];
        const bf16x8 a1 = *(const bf16x8*)&Wl[16 + lr][k * 32 + lg * 8];
        bf16x8 bf[2][2];
#pragma unroll
        for (int e = 0; e < 2; ++e)
#pragma unroll
            for (int s = 0; s < 2; ++s) {
                const int row = wn + s * 16 + lr;
                bf[e][s] = *(const bf16x8*)&Xl[k & 1][row][((e * 4 + lg) ^ (row & 7)) * 8];
            }
#pragma unroll
        for (int e = 0; e < 2; ++e)
#pragma unroll
            for (int s = 0; s < 2; ++s) {
                acc[0][e][s] = __builtin_amdgcn_mfma_f32_16x16x32_bf16(a0, bf[e][s], acc[0][e][s], 0, 0, 0);
                acc[1][e][s] = __builtin_amdgcn_mfma_f32_16x16x32_bf16(a1, bf[e][s], acc[1][e][s], 0, 0, 0);
            }
    }

#pragma unroll
    for (int m = 0; m < 2; ++m)
#pragma unroll
        for (int e = 0; e < 2; ++e)
#pragma unroll
            for (int s = 0; s < 2; ++s)
#pragma unroll
                for (int r = 0; r < 4; ++r) {
                    const int o = m * 16 + lg * 4 + r;
                    const int b = p * 2 + e;
                    const int n = n0 + wn + s * 16 + lr;
                    const float v = acc[m][e][s][r];
                    out[((size_t)(b * COUT + o)) * NN + n] = v > 0.f ? v : 0.f;
                }
}

extern "C" void kernel_launch(void* const* d_in, const int* in_sizes, int n_in,
                              void* d_out, int out_size, void* d_ws, size_t ws_size,
                              hipStream_t stream) {
    const float* inp  = (const float*)d_in[0];
    const float* w    = (const float*)d_in[1];
    const float* bias = (const float*)d_in[2];
    const int*   tbl  = (const int*)d_in[3];

    ushort_t* xbp = (ushort_t*)d_ws;                             // 2 pairs x 10.49 MB
    float* out = (float*)d_out;

    k_transpose<<<dim3(NN / 64, B_), 256, 0, stream>>>(inp, xbp);
    k_main<<<2 * (NN / NT), 256, 0, stream>>>(xbp, w, bias, tbl, out);
}

// Round 11
// 47.192 us; speedup vs baseline: 1.3798x; 1.1178x over previous
//
#include <hip/hip_runtime.h>
#include <stdint.h>

#define B_   4
#define CIN  32
#define COUT 32
#define NN   81920
#define KK   10
#define NT   128          // n-tile per block (4 waves x 32 rows each)

typedef unsigned short ushort_t;
typedef __attribute__((ext_vector_type(8))) short bf16x8;
typedef __attribute__((ext_vector_type(4))) float f32x4;

// float -> bf16 bits, round-to-nearest-even
__device__ __host__ __forceinline__ ushort_t f2bf(float f) {
    union { float f; unsigned int u; } v; v.f = f;
    unsigned int r = (v.u + 0x7FFFu + ((v.u >> 16) & 1u)) >> 16;
    return (ushort_t)r;
}

__device__ __forceinline__ void gl_lds16(const void* g, void* lds) {
    auto gp = (const __attribute__((address_space(1))) unsigned int*)((uintptr_t)g);
    auto lp = (__attribute__((address_space(3))) unsigned int*)((uintptr_t)lds);
    __builtin_amdgcn_global_load_lds(gp, lp, 16, 0, 0);
}

// ---------- Kernel 1: transpose+convert (B,C,N) f32 -> xbp (pair,N,e,C) bf16 ----------
__global__ __launch_bounds__(256) void k_transpose(const float* __restrict__ in,
                                                   ushort_t* __restrict__ xbp) {
    __shared__ float tile[32][65];
    const int b   = blockIdx.y;        // 0..3
    const int p   = b >> 1, e = b & 1;
    const int n0  = blockIdx.x * 64;
    const int tid = threadIdx.x;

#pragma unroll
    for (int i = 0; i < 8; ++i) {
        const int c = i * 4 + (tid >> 6);
        const int n = tid & 63;
        tile[c][n] = in[((size_t)b * CIN + c) * NN + n0 + n];
    }
    __syncthreads();
#pragma unroll
    for (int i = 0; i < 4; ++i) {
        const int n  = i * 16 + (tid >> 4);
        const int cp = tid & 15;
        const unsigned int u0 = f2bf(tile[2 * cp][n]);
        const unsigned int u1 = f2bf(tile[2 * cp + 1][n]);
        *(unsigned int*)&xbp[(size_t)p * NN * 64 + (size_t)(n0 + n) * 64 + e * 32 + 2 * cp]
            = u0 | (u1 << 16);
    }
}

// ---------- Kernel 2: weight -> A-fragment layout wb[k][f][lane][8] bf16 ----------
// Lane (lr=lane&15, lg=lane>>4) of frag f needs w[o=f*16+lr][c=lg*8+j][k].
__global__ void k_wprep(const float* __restrict__ w, ushort_t* __restrict__ wb) {
    const int idx = blockIdx.x * 256 + threadIdx.x;
    if (idx < KK * 2 * 64 * 8) {
        const int j    = idx & 7;
        const int lane = (idx >> 3) & 63;
        const int f    = (idx >> 9) & 1;
        const int k    = idx >> 10;
        const int o    = f * 16 + (lane & 15);
        const int c    = (lane >> 4) * 8 + j;
        wb[idx] = f2bf(w[((size_t)o * CIN + c) * KK + k]);
    }
}

// ---------- Kernel 3: pair-packed gathered conv, depth-2 pipeline, NO barriers ----------
// 3 wave-private X-buffers (LDS 48KB -> 3 blocks/CU); A-frags via inline-asm
// loads 2-ahead in rotating regs; counted vmcnt(12/6/0); stage = 6 vmem ops.
__global__ __launch_bounds__(256, 4) void k_main(const ushort_t* __restrict__ xbp,
                                                 const ushort_t* __restrict__ wb,
                                                 const float* __restrict__ bias,
                                                 const int* __restrict__ tbl,
                                                 float* __restrict__ out) {
    __shared__ ushort_t Xl[3][NT][64];     // 49,152 B total; 128B rows

    const int tid = threadIdx.x;
    const int bid = blockIdx.x;
    const int p    = (bid >> 2) & 1;       // pair -> XCDs {0-3} / {4-7}
    const int tile = (bid >> 3) * 4 + (bid & 3);
    const int n0   = tile * NT;

    const int lane = tid & 63;
    const int wid  = tid >> 6;
    const int wn   = wid * 32;             // wave's private 32-row slice
    const int lr   = lane & 15;
    const int lg   = lane >> 4;
    const int g    = lane >> 3;            // line-group (8 lanes per 128B line)
    const int csw  = (lane & 7) ^ g;       // source chunk for XOR-swizzled LDS

    // wave's 320 table entries -> 5 regs/lane
    int tq[5];
#pragma unroll
    for (int j = 0; j < 5; ++j) {
        const int idx = j * 64 + lane;
        tq[j] = tbl[(size_t)(idx >> 5) * NN + n0 + wn + (idx & 31)];
    }

    // bias -> acc (C loads, consumed immediately; retire before asm loads below)
    f32x4 acc[2][2][2];                    // [m][e][s]
#pragma unroll
    for (int m = 0; m < 2; ++m) {
        f32x4 bv;
#pragma unroll
        for (int r = 0; r < 4; ++r) bv[r] = bias[m * 16 + lg * 4 + r];
#pragma unroll
        for (int e = 0; e < 2; ++e) { acc[m][e][0] = bv; acc[m][e][1] = bv; }
    }

    const ushort_t* pb  = xbp + (size_t)p * NN * 64;
    const uint64_t wB64 = (uint64_t)wb;
    const uint32_t aoffL = (uint32_t)(lane * 16);

    bf16x8 af0[3], af1[3];

#define STAGEX(kk, buf)                                                         \
    do {                                                                        \
        _Pragma("unroll")                                                       \
        for (int m_ = 0; m_ < 4; ++m_) {                                        \
            const int idx_ = (kk) * 32 + m_ * 8;                                \
            const int t_ = __shfl(tq[idx_ >> 6], (idx_ & 63) + g, 64);          \
            gl_lds16(pb + (size_t)t_ * 64 + csw * 8,                            \
                     &Xl[buf][wn + m_ * 8 + g][(lane & 7) * 8]);                \
        }                                                                       \
    } while (0)

#define STAGEA(kk)                                                              \
    do {                                                                        \
        asm volatile("global_load_dwordx4 %0, %1, %2"                           \
                     : "=v"(af0[(kk) % 3])                                      \
                     : "v"(aoffL + (uint32_t)((kk) * 2048)), "s"(wB64));        \
        asm volatile("global_load_dwordx4 %0, %1, %2"                           \
                     : "=v"(af1[(kk) % 3])                                      \
                     : "v"(aoffL + (uint32_t)((kk) * 2048 + 1024)), "s"(wB64)); \
    } while (0)

    // prologue: 2 stages in flight (12 vmem ops)
    __builtin_amdgcn_sched_barrier(0);
    STAGEX(0, 0); STAGEA(0);
    __builtin_amdgcn_sched_barrier(0);
    STAGEX(1, 1); STAGEA(1);
    __builtin_amdgcn_sched_barrier(0);

#pragma unroll
    for (int k = 0; k < KK; ++k) {
        if (k + 2 < KK) { STAGEX(k + 2, (k + 2) % 3); STAGEA(k + 2); }
        __builtin_amdgcn_sched_barrier(0);
        asm volatile("s_waitcnt vmcnt(%0)"
                     :: "i"(6 * ((KK - 1 - k) < 2 ? (KK - 1 - k) : 2)) : "memory");
        __builtin_amdgcn_sched_barrier(0);

        bf16x8 bf[2][2];
#pragma unroll
        for (int e = 0; e < 2; ++e)
#pragma unroll
            for (int s = 0; s < 2; ++s) {
                const int row = wn + s * 16 + lr;
                bf[e][s] = *(const bf16x8*)&Xl[k % 3][row][((e * 4 + lg) ^ (row & 7)) * 8];
            }
#pragma unroll
        for (int e = 0; e < 2; ++e)
#pragma unroll
            for (int s = 0; s < 2; ++s) {
                acc[0][e][s] = __builtin_amdgcn_mfma_f32_16x16x32_bf16(af0[k % 3], bf[e][s], acc[0][e][s], 0, 0, 0);
                acc[1][e][s] = __builtin_amdgcn_mfma_f32_16x16x32_bf16(af1[k % 3], bf[e][s], acc[1][e][s], 0, 0, 0);
            }
    }
#undef STAGEX
#undef STAGEA

#pragma unroll
    for (int m = 0; m < 2; ++m)
#pragma unroll
        for (int e = 0; e < 2; ++e)
#pragma unroll
            for (int s = 0; s < 2; ++s)
#pragma unroll
                for (int r = 0; r < 4; ++r) {
                    const int o = m * 16 + lg * 4 + r;
                    const int b = p * 2 + e;
                    const int n = n0 + wn + s * 16 + lr;
                    const float v = acc[m][e][s][r];
                    out[((size_t)(b * COUT + o)) * NN + n] = v > 0.f ? v : 0.f;
                }
}

extern "C" void kernel_launch(void* const* d_in, const int* in_sizes, int n_in,
                              void* d_out, int out_size, void* d_ws, size_t ws_size,
                              hipStream_t stream) {
    const float* inp  = (const float*)d_in[0];
    const float* w    = (const float*)d_in[1];
    const float* bias = (const float*)d_in[2];
    const int*   tbl  = (const int*)d_in[3];

    ushort_t* xbp = (ushort_t*)d_ws;                             // 20.97 MB
    ushort_t* wb  = (ushort_t*)((char*)d_ws + (size_t)2 * NN * 64 * sizeof(ushort_t));
    float* out = (float*)d_out;

    k_transpose<<<dim3(NN / 64, B_), 256, 0, stream>>>(inp, xbp);
    k_wprep<<<(KK * 2 * 64 * 8 + 255) / 256, 256, 0, stream>>>(w, wb);
    k_main<<<2 * (NN / NT), 256, 0, stream>>>(xbp, wb, bias, tbl, out);
}